// Round 2
// baseline (4354.411 us; speedup 1.0000x reference)
//
#include <hip/hip_runtime.h>
#include <math.h>

#define NN 50000
#define NE 1600000

// edge_index may arrive as int64 (reference dtype) or int32 (harness-normalized).
// Detect at runtime: int64 little-endian view as u32 has zero high words.
__device__ __forceinline__ long long edge_get(const void* ei, int is64, long long i) {
    return is64 ? ((const long long*)ei)[i] : (long long)((const int*)ei)[i];
}

__global__ void k_detect(const unsigned int* __restrict__ e, int* flag) {
    unsigned int v = e[2 * threadIdx.x + 1];
    unsigned long long m = __ballot(v != 0u);
    if (threadIdx.x == 0) *flag = (m == 0ull) ? 1 : 0;
}

__global__ void k_initdeg(float* deg) {
    int i = blockIdx.x * 256 + threadIdx.x;
    if (i < NN) deg[i] = 1.0f;  // self-loop
}

__global__ void k_deg(const void* __restrict__ ei, const int* __restrict__ flag,
                      float* __restrict__ deg) {
    int is64 = *flag;
    int e = blockIdx.x * 256 + threadIdx.x;
    if (e < NE) {
        int d = (int)edge_get(ei, is64, (long long)NE + e);
        atomicAdd(&deg[d], 1.0f);
    }
}

__global__ void k_rsqrt(float* deg) {
    int i = blockIdx.x * 256 + threadIdx.x;
    if (i < NN) deg[i] = rsqrtf(deg[i]);  // deg >= 1 always
}

// out[r][c] = dinv[r] * sum_k X[r][k]*W[k][c].   BM=64, KT=16, block=256 (16x16),
// each thread: 4 rows x (CN/16) cols, strided so LDS reads are broadcast/conflict-free.
template <int K, int CN>
__global__ __launch_bounds__(256) void k_gemm_scale(const float* __restrict__ X,
                                                    const float* __restrict__ W,
                                                    const float* __restrict__ dinv,
                                                    float* __restrict__ out) {
    const int BM = 64, KT = 16;
    const int TN = CN / 16;
    __shared__ float As[KT][BM + 1];   // +1 pad: writers hit distinct banks
    __shared__ float Bs[KT][CN + 1];
    int tid = threadIdx.x;
    int tx = tid & 15, ty = tid >> 4;
    int row0 = blockIdx.x * BM;
    float acc[4][TN];
#pragma unroll
    for (int a = 0; a < 4; a++)
#pragma unroll
        for (int b = 0; b < TN; b++) acc[a][b] = 0.f;

    for (int k0 = 0; k0 < K; k0 += KT) {
#pragma unroll
        for (int j = 0; j < (KT * BM) / 256; j++) {
            int idx = tid + 256 * j;
            int kk = idx & 15, m = idx >> 4;
            int r = row0 + m;
            As[kk][m] = (r < NN) ? X[(long long)r * K + (k0 + kk)] : 0.f;
        }
#pragma unroll
        for (int j = 0; j < (KT * CN) / 256; j++) {
            int idx = tid + 256 * j;
            int kk = idx / CN, c = idx % CN;
            Bs[kk][c] = W[(long long)(k0 + kk) * CN + c];
        }
        __syncthreads();
#pragma unroll
        for (int kk = 0; kk < KT; kk++) {
            float a[4], b[TN];
#pragma unroll
            for (int mi = 0; mi < 4; mi++) a[mi] = As[kk][ty + 16 * mi];
#pragma unroll
            for (int ni = 0; ni < TN; ni++) b[ni] = Bs[kk][tx + 16 * ni];
#pragma unroll
            for (int mi = 0; mi < 4; mi++)
#pragma unroll
                for (int ni = 0; ni < TN; ni++)
                    acc[mi][ni] = fmaf(a[mi], b[ni], acc[mi][ni]);
        }
        __syncthreads();
    }
#pragma unroll
    for (int mi = 0; mi < 4; mi++) {
        int r = row0 + ty + 16 * mi;
        if (r < NN) {
            float s = dinv[r];
#pragma unroll
            for (int ni = 0; ni < TN; ni++)
                out[(long long)r * CN + tx + 16 * ni] = s * acc[mi][ni];
        }
    }
}

// One edge handled by CN/4 lanes, each doing a float4 gather + 4 f32 atomics.
template <int CN>
__global__ __launch_bounds__(256) void k_scatter(const float4* __restrict__ h,
                                                 const void* __restrict__ ei,
                                                 const int* __restrict__ flag,
                                                 float* __restrict__ agg) {
    const int LPE = CN / 4;
    int is64 = *flag;
    long long t = (long long)blockIdx.x * 256 + threadIdx.x;
    long long e = t / LPE;
    int c4 = (int)(t & (LPE - 1));
    if (e >= NE) return;
    int s = (int)edge_get(ei, is64, e);
    int d = (int)edge_get(ei, is64, (long long)NE + e);
    float4 v = h[(long long)s * LPE + c4];
    float* ap = agg + (long long)d * CN + 4 * c4;
    atomicAdd(ap + 0, v.x);
    atomicAdd(ap + 1, v.y);
    atomicAdd(ap + 2, v.z);
    atomicAdd(ap + 3, v.w);
}

// out1 = relu(dinv[i]*(agg + h') + b), written in-place into agg.
__global__ __launch_bounds__(256) void k_epi1(float* __restrict__ agg,
                                              const float* __restrict__ h,
                                              const float* __restrict__ dinv,
                                              const float* __restrict__ b) {
    long long t = (long long)blockIdx.x * 256 + threadIdx.x;
    if (t >= (long long)NN * 128) return;
    int i = (int)(t >> 7), c = (int)(t & 127);
    float v = dinv[i] * (agg[t] + h[t]) + b[c];
    agg[t] = fmaxf(v, 0.f);
}

// t = dinv*(agg+h')+b2; log_softmax over 64 channels; one wave per row.
__global__ __launch_bounds__(256) void k_final(const float* __restrict__ agg,
                                               const float* __restrict__ h,
                                               const float* __restrict__ dinv,
                                               const float* __restrict__ b,
                                               float* __restrict__ out) {
    int lane = threadIdx.x & 63;
    int row = blockIdx.x * 4 + (threadIdx.x >> 6);
    if (row >= NN) return;
    long long idx = (long long)row * 64 + lane;
    float t = dinv[row] * (agg[idx] + h[idx]) + b[lane];
    float m = t;
#pragma unroll
    for (int o = 32; o; o >>= 1) m = fmaxf(m, __shfl_xor(m, o));
    float ex = __expf(t - m);
    float s2 = ex;
#pragma unroll
    for (int o = 32; o; o >>= 1) s2 += __shfl_xor(s2, o);
    out[idx] = (t - m) - logf(s2);
}

extern "C" void kernel_launch(void* const* d_in, const int* in_sizes, int n_in,
                              void* d_out, int out_size, void* d_ws, size_t ws_size,
                              hipStream_t stream) {
    const float* x  = (const float*)d_in[0];
    const void*  ei = d_in[1];
    const float* W1 = (const float*)d_in[2];
    const float* b1 = (const float*)d_in[3];
    const float* W2 = (const float*)d_in[4];
    const float* b2 = (const float*)d_in[5];
    float* out = (float*)d_out;

    char* ws = (char*)d_ws;
    float* dinv = (float*)ws;                       // 200 KB
    int*   flag = (int*)(ws + 204800);
    float* h1   = (float*)(ws + (size_t)(1 << 20));          // 25.6 MB (h1, then h2)
    float* agg  = (float*)(ws + (size_t)(28) * (1 << 20));   // 25.6 MB (agg1->out1, then agg2)

    k_detect<<<1, 64, 0, stream>>>((const unsigned int*)ei, flag);
    k_initdeg<<<(NN + 255) / 256, 256, 0, stream>>>(dinv);
    k_deg<<<(NE + 255) / 256, 256, 0, stream>>>(ei, flag, dinv);
    k_rsqrt<<<(NN + 255) / 256, 256, 0, stream>>>(dinv);

    // Layer 1
    k_gemm_scale<256, 128><<<(NN + 63) / 64, 256, 0, stream>>>(x, W1, dinv, h1);
    hipMemsetAsync(agg, 0, (size_t)NN * 128 * 4, stream);
    k_scatter<128><<<(int)(((long long)NE * 32 + 255) / 256), 256, 0, stream>>>(
        (const float4*)h1, ei, flag, agg);
    k_epi1<<<(int)(((long long)NN * 128 + 255) / 256), 256, 0, stream>>>(agg, h1, dinv, b1);

    // Layer 2
    k_gemm_scale<128, 64><<<(NN + 63) / 64, 256, 0, stream>>>(agg, W2, dinv, h1);
    hipMemsetAsync(agg, 0, (size_t)NN * 64 * 4, stream);
    k_scatter<64><<<(int)(((long long)NE * 16 + 255) / 256), 256, 0, stream>>>(
        (const float4*)h1, ei, flag, agg);
    k_final<<<(NN + 3) / 4, 256, 0, stream>>>(agg, h1, dinv, b2, out);
}

// Round 4
// 532.653 us; speedup vs baseline: 8.1749x; 8.1749x over previous
//
#include <hip/hip_runtime.h>
#include <math.h>

#define NN 50000
#define NE 1600000
#define NB 196  // ceil(NN/256)

// edge_index may arrive as int64 (reference dtype) or int32 (harness-normalized).
__device__ __forceinline__ int edge_get(const void* ei, int is64, long long i) {
    return is64 ? (int)((const long long*)ei)[i] : ((const int*)ei)[i];
}

__global__ void k_detect(const unsigned int* __restrict__ e, int* flag) {
    unsigned int v = e[2 * threadIdx.x + 1];
    unsigned long long m = __ballot(v != 0u);
    if (threadIdx.x == 0) *flag = (m == 0ull) ? 1 : 0;
}

// ---- CSR build ----
__global__ __launch_bounds__(256) void k_count(const void* __restrict__ ei,
                                               const int* __restrict__ flag,
                                               int* __restrict__ cnt) {
    int is64 = *flag;
    int e = blockIdx.x * 256 + threadIdx.x;
    if (e < NE) atomicAdd(&cnt[edge_get(ei, is64, (long long)NE + e)], 1);
}

__global__ __launch_bounds__(256) void k_scan1(const int* __restrict__ cnt,
                                               int* __restrict__ rowstart,
                                               int* __restrict__ bsum) {
    __shared__ int s[256];
    int tid = threadIdx.x, i = blockIdx.x * 256 + tid;
    int v = (i < NN) ? cnt[i] : 0;
    s[tid] = v;
    __syncthreads();
#pragma unroll
    for (int off = 1; off < 256; off <<= 1) {
        int t = (tid >= off) ? s[tid - off] : 0;
        __syncthreads();
        if (tid >= off) s[tid] += t;
        __syncthreads();
    }
    if (i < NN) rowstart[i] = s[tid] - v;  // exclusive within block
    if (tid == 255) bsum[blockIdx.x] = s[255];
}

__global__ __launch_bounds__(256) void k_scan2(int* __restrict__ bsum) {
    __shared__ int s[256];
    int tid = threadIdx.x;
    int v = (tid < NB) ? bsum[tid] : 0;
    s[tid] = v;
    __syncthreads();
#pragma unroll
    for (int off = 1; off < 256; off <<= 1) {
        int t = (tid >= off) ? s[tid - off] : 0;
        __syncthreads();
        if (tid >= off) s[tid] += t;
        __syncthreads();
    }
    if (tid < NB) bsum[tid] = s[tid] - v;  // exclusive over blocks
}

__global__ __launch_bounds__(256) void k_scan3(int* __restrict__ rowstart,
                                               const int* __restrict__ bsum) {
    int i = blockIdx.x * 256 + threadIdx.x;
    if (i < NN) rowstart[i] += bsum[blockIdx.x];
}

__global__ __launch_bounds__(256) void k_dinv(const int* __restrict__ cnt,
                                              float* __restrict__ dinv) {
    int i = blockIdx.x * 256 + threadIdx.x;
    if (i < NN) dinv[i] = rsqrtf((float)cnt[i] + 1.0f);  // +1 self-loop
}

__global__ __launch_bounds__(256) void k_fill(const void* __restrict__ ei,
                                              const int* __restrict__ flag,
                                              const int* __restrict__ rowstart,
                                              int* __restrict__ cur,
                                              int* __restrict__ csr) {
    int is64 = *flag;
    int e = blockIdx.x * 256 + threadIdx.x;
    if (e < NE) {
        int s = edge_get(ei, is64, e);
        int d = edge_get(ei, is64, (long long)NE + e);
        int pos = rowstart[d] + atomicAdd(&cur[d], 1);
        csr[pos] = s;
    }
}

// ---- GEMM with dinv-row-scale epilogue: out[r][c] = dinv[r] * (X@W)[r][c] ----
template <int K, int CN>
__global__ __launch_bounds__(256) void k_gemm_scale(const float* __restrict__ X,
                                                    const float* __restrict__ W,
                                                    const float* __restrict__ dinv,
                                                    float* __restrict__ out) {
    const int BM = 64, KT = 16;
    const int TN = CN / 16;
    __shared__ float As[KT][BM + 1];
    __shared__ float Bs[KT][CN + 1];
    int tid = threadIdx.x;
    int tx = tid & 15, ty = tid >> 4;
    int row0 = blockIdx.x * BM;
    float acc[4][TN];
#pragma unroll
    for (int a = 0; a < 4; a++)
#pragma unroll
        for (int b = 0; b < TN; b++) acc[a][b] = 0.f;

    for (int k0 = 0; k0 < K; k0 += KT) {
#pragma unroll
        for (int j = 0; j < (KT * BM) / 256; j++) {
            int idx = tid + 256 * j;
            int kk = idx & 15, m = idx >> 4;
            int r = row0 + m;
            As[kk][m] = (r < NN) ? X[(long long)r * K + (k0 + kk)] : 0.f;
        }
#pragma unroll
        for (int j = 0; j < (KT * CN) / 256; j++) {
            int idx = tid + 256 * j;
            int kk = idx / CN, c = idx % CN;
            Bs[kk][c] = W[(long long)(k0 + kk) * CN + c];
        }
        __syncthreads();
#pragma unroll
        for (int kk = 0; kk < KT; kk++) {
            float a[4], b[TN];
#pragma unroll
            for (int mi = 0; mi < 4; mi++) a[mi] = As[kk][ty + 16 * mi];
#pragma unroll
            for (int ni = 0; ni < TN; ni++) b[ni] = Bs[kk][tx + 16 * ni];
#pragma unroll
            for (int mi = 0; mi < 4; mi++)
#pragma unroll
                for (int ni = 0; ni < TN; ni++)
                    acc[mi][ni] = fmaf(a[mi], b[ni], acc[mi][ni]);
        }
        __syncthreads();
    }
#pragma unroll
    for (int mi = 0; mi < 4; mi++) {
        int r = row0 + ty + 16 * mi;
        if (r < NN) {
            float s = dinv[r];
#pragma unroll
            for (int ni = 0; ni < TN; ni++)
                out[(long long)r * CN + tx + 16 * ni] = s * acc[mi][ni];
        }
    }
}

// ---- Layer-1 aggregate: out = relu(dinv[i]*(self + sum_in h') + b). float4, 32 lanes/node ----
__global__ __launch_bounds__(256) void k_gather_relu(const float4* __restrict__ h4,
                                                     const int* __restrict__ csr,
                                                     const int* __restrict__ rowstart,
                                                     const int* __restrict__ cnt,
                                                     const float* __restrict__ dinv,
                                                     const float4* __restrict__ b4,
                                                     float4* __restrict__ out4) {
    int tid = threadIdx.x;
    int node = blockIdx.x * 8 + (tid >> 5);  // 8 nodes/block, 32 lanes/node
    int c4 = tid & 31;
    if (node >= NN) return;
    int beg = rowstart[node], n = cnt[node];
    float4 s0 = h4[(long long)node * 32 + c4];  // self-loop term
    float4 s1 = {0, 0, 0, 0}, s2 = {0, 0, 0, 0}, s3 = {0, 0, 0, 0};
    int j = 0;
    for (; j + 3 < n; j += 4) {
        int a0 = csr[beg + j], a1 = csr[beg + j + 1], a2 = csr[beg + j + 2], a3 = csr[beg + j + 3];
        float4 v0 = h4[(long long)a0 * 32 + c4], v1 = h4[(long long)a1 * 32 + c4];
        float4 v2 = h4[(long long)a2 * 32 + c4], v3 = h4[(long long)a3 * 32 + c4];
        s0.x += v0.x; s0.y += v0.y; s0.z += v0.z; s0.w += v0.w;
        s1.x += v1.x; s1.y += v1.y; s1.z += v1.z; s1.w += v1.w;
        s2.x += v2.x; s2.y += v2.y; s2.z += v2.z; s2.w += v2.w;
        s3.x += v3.x; s3.y += v3.y; s3.z += v3.z; s3.w += v3.w;
    }
    for (; j < n; j++) {
        float4 v = h4[(long long)csr[beg + j] * 32 + c4];
        s0.x += v.x; s0.y += v.y; s0.z += v.z; s0.w += v.w;
    }
    float d = dinv[node];
    float4 bb = b4[c4];
    float4 r;
    r.x = fmaxf(fmaf(d, s0.x + s1.x + s2.x + s3.x, bb.x), 0.f);
    r.y = fmaxf(fmaf(d, s0.y + s1.y + s2.y + s3.y, bb.y), 0.f);
    r.z = fmaxf(fmaf(d, s0.z + s1.z + s2.z + s3.z, bb.z), 0.f);
    r.w = fmaxf(fmaf(d, s0.w + s1.w + s2.w + s3.w, bb.w), 0.f);
    out4[(long long)node * 32 + c4] = r;
}

// ---- Layer-2 aggregate + bias + log_softmax. 64 lanes (one wave) per node ----
__global__ __launch_bounds__(256) void k_gather_lsm(const float* __restrict__ h,
                                                    const int* __restrict__ csr,
                                                    const int* __restrict__ rowstart,
                                                    const int* __restrict__ cnt,
                                                    const float* __restrict__ dinv,
                                                    const float* __restrict__ b,
                                                    float* __restrict__ out) {
    int lane = threadIdx.x & 63;
    int node = blockIdx.x * 4 + (threadIdx.x >> 6);
    if (node >= NN) return;
    int beg = rowstart[node], n = cnt[node];
    float s0 = h[(long long)node * 64 + lane];  // self
    float s1 = 0.f, s2 = 0.f, s3 = 0.f;
    int j = 0;
    for (; j + 3 < n; j += 4) {
        int a0 = csr[beg + j], a1 = csr[beg + j + 1], a2 = csr[beg + j + 2], a3 = csr[beg + j + 3];
        s0 += h[(long long)a0 * 64 + lane];
        s1 += h[(long long)a1 * 64 + lane];
        s2 += h[(long long)a2 * 64 + lane];
        s3 += h[(long long)a3 * 64 + lane];
    }
    for (; j < n; j++) s0 += h[(long long)csr[beg + j] * 64 + lane];
    float t = fmaf(dinv[node], (s0 + s1) + (s2 + s3), b[lane]);
    float m = t;
#pragma unroll
    for (int o = 32; o; o >>= 1) m = fmaxf(m, __shfl_xor(m, o));
    float ex = __expf(t - m);
#pragma unroll
    for (int o = 32; o; o >>= 1) ex += __shfl_xor(ex, o);
    out[(long long)node * 64 + lane] = (t - m) - logf(ex);
}

extern "C" void kernel_launch(void* const* d_in, const int* in_sizes, int n_in,
                              void* d_out, int out_size, void* d_ws, size_t ws_size,
                              hipStream_t stream) {
    const float* x  = (const float*)d_in[0];
    const void*  ei = d_in[1];
    const float* W1 = (const float*)d_in[2];
    const float* b1 = (const float*)d_in[3];
    const float* W2 = (const float*)d_in[4];
    const float* b2 = (const float*)d_in[5];
    float* out = (float*)d_out;

    char* ws = (char*)d_ws;
    float* dinv     = (float*)(ws + 0x000000);   // 200 KB
    int*   flag     = (int*)  (ws + 0x040000);
    int*   cnt      = (int*)  (ws + 0x050000);   // 200 KB
    int*   rowstart = (int*)  (ws + 0x090000);   // 200 KB
    int*   cur      = (int*)  (ws + 0x0D0000);   // 200 KB
    int*   bsum     = (int*)  (ws + 0x110000);   // 784 B
    int*   csr      = (int*)  (ws + 0x120000);   // 6.4 MB
    float* h1       = (float*)(ws + 0x740000);   // 25.6 MB (h', then h2')
    float* out1     = (float*)(ws + 0x2040000);  // 25.6 MB

    k_detect<<<1, 64, 0, stream>>>((const unsigned int*)ei, flag);
    hipMemsetAsync(cnt, 0, (size_t)NN * 4, stream);
    hipMemsetAsync(cur, 0, (size_t)NN * 4, stream);
    k_count<<<(NE + 255) / 256, 256, 0, stream>>>(ei, flag, cnt);
    k_scan1<<<NB, 256, 0, stream>>>(cnt, rowstart, bsum);
    k_scan2<<<1, 256, 0, stream>>>(bsum);
    k_scan3<<<NB, 256, 0, stream>>>(rowstart, bsum);
    k_dinv<<<NB, 256, 0, stream>>>(cnt, dinv);
    k_fill<<<(NE + 255) / 256, 256, 0, stream>>>(ei, flag, rowstart, cur, csr);

    // Layer 1: h1 = dinv .* (x@W1); out1 = relu(dinv.*(agg+self) + b1)
    k_gemm_scale<256, 128><<<(NN + 63) / 64, 256, 0, stream>>>(x, W1, dinv, h1);
    k_gather_relu<<<(NN + 7) / 8, 256, 0, stream>>>((const float4*)h1, csr, rowstart, cnt,
                                                    dinv, (const float4*)b1, (float4*)out1);

    // Layer 2: h2 = dinv .* (out1@W2); out = log_softmax(dinv.*(agg+self) + b2)
    k_gemm_scale<128, 64><<<(NN + 63) / 64, 256, 0, stream>>>(out1, W2, dinv, h1);
    k_gather_lsm<<<(NN + 3) / 4, 256, 0, stream>>>(h1, csr, rowstart, cnt, dinv, b2, out);
}

// Round 6
// 452.229 us; speedup vs baseline: 9.6288x; 1.1778x over previous
//
#include <hip/hip_runtime.h>
#include <math.h>

#define NN 50000
#define NE 1600000
#define NB 196  // ceil(NN/256)

// ---- bf16 helpers (bit-level, RNE pack) ----
__device__ __forceinline__ float blo(unsigned u) { return __uint_as_float(u << 16); }
__device__ __forceinline__ float bhi(unsigned u) { return __uint_as_float(u & 0xffff0000u); }
__device__ __forceinline__ unsigned bpack(float a, float b) {
    unsigned ua = __float_as_uint(a), ub = __float_as_uint(b);
    ua += 0x7fffu + ((ua >> 16) & 1u);
    ub += 0x7fffu + ((ub >> 16) & 1u);
    return (ua >> 16) | (ub & 0xffff0000u);
}

// edge_index may arrive as int64 (reference dtype) or int32 (harness-normalized).
__device__ __forceinline__ int edge_get(const void* ei, int is64, long long i) {
    return is64 ? (int)((const long long*)ei)[i] : ((const int*)ei)[i];
}

__global__ void k_detect(const unsigned int* __restrict__ e, int* flag) {
    unsigned int v = e[2 * threadIdx.x + 1];
    unsigned long long m = __ballot(v != 0u);
    if (threadIdx.x == 0) *flag = (m == 0ull) ? 1 : 0;
}

// ---- CSR build ----
__global__ __launch_bounds__(256) void k_count(const void* __restrict__ ei,
                                               const int* __restrict__ flag,
                                               int* __restrict__ cnt) {
    int is64 = *flag;
    int e = blockIdx.x * 256 + threadIdx.x;
    if (e < NE) atomicAdd(&cnt[edge_get(ei, is64, (long long)NE + e)], 1);
}

__global__ __launch_bounds__(256) void k_scan1(const int* __restrict__ cnt,
                                               int* __restrict__ rowstart,
                                               int* __restrict__ bsum) {
    __shared__ int s[256];
    int tid = threadIdx.x, i = blockIdx.x * 256 + tid;
    int v = (i < NN) ? cnt[i] : 0;
    s[tid] = v;
    __syncthreads();
#pragma unroll
    for (int off = 1; off < 256; off <<= 1) {
        int t = (tid >= off) ? s[tid - off] : 0;
        __syncthreads();
        if (tid >= off) s[tid] += t;
        __syncthreads();
    }
    if (i < NN) rowstart[i] = s[tid] - v;
    if (tid == 255) bsum[blockIdx.x] = s[255];
}

__global__ __launch_bounds__(256) void k_scan2(int* __restrict__ bsum) {
    __shared__ int s[256];
    int tid = threadIdx.x;
    int v = (tid < NB) ? bsum[tid] : 0;
    s[tid] = v;
    __syncthreads();
#pragma unroll
    for (int off = 1; off < 256; off <<= 1) {
        int t = (tid >= off) ? s[tid - off] : 0;
        __syncthreads();
        if (tid >= off) s[tid] += t;
        __syncthreads();
    }
    if (tid < NB) bsum[tid] = s[tid] - v;
}

// rowstart += block offset; also seed cur = rowstart (fused cursor init)
__global__ __launch_bounds__(256) void k_scan3(int* __restrict__ rowstart,
                                               const int* __restrict__ bsum,
                                               int* __restrict__ cur) {
    int i = blockIdx.x * 256 + threadIdx.x;
    if (i < NN) {
        int v = rowstart[i] + bsum[blockIdx.x];
        rowstart[i] = v;
        cur[i] = v;
    }
}

__global__ __launch_bounds__(256) void k_dinv(const int* __restrict__ cnt,
                                              float* __restrict__ dinv) {
    int i = blockIdx.x * 256 + threadIdx.x;
    if (i < NN) dinv[i] = rsqrtf((float)cnt[i] + 1.0f);
}

__global__ __launch_bounds__(256) void k_fill(const void* __restrict__ ei,
                                              const int* __restrict__ flag,
                                              int* __restrict__ cur,
                                              int* __restrict__ csr) {
    int is64 = *flag;
    int e = blockIdx.x * 256 + threadIdx.x;
    if (e < NE) {
        int s = edge_get(ei, is64, e);
        int d = edge_get(ei, is64, (long long)NE + e);
        csr[atomicAdd(&cur[d], 1)] = s;
    }
}

// ---- GEMM with dinv-row-scale epilogue, bf16 output.
// BM=64 rows, full CN cols, 256 threads (16x16), per-thread 4 rows x (CN/64 groups of 4 cols).
template <int K, int CN, bool XBF>
__global__ __launch_bounds__(256) void k_gemm_scale(const void* __restrict__ Xv,
                                                    const float* __restrict__ W,
                                                    const float* __restrict__ dinv,
                                                    unsigned int* __restrict__ outb) {
    const int BM = 64, KT = 16, G = CN / 64;
    __shared__ float As[KT][BM + 4];
    __shared__ float Bs[KT][CN];
    int tid = threadIdx.x;
    int tx = tid & 15, ty = tid >> 4;
    int row0 = blockIdx.x * BM;
    float acc[4][G * 4];
#pragma unroll
    for (int a = 0; a < 4; a++)
#pragma unroll
        for (int b = 0; b < G * 4; b++) acc[a][b] = 0.f;

    for (int k0 = 0; k0 < K; k0 += KT) {
        // stage A (transposed to As[k][m])
        if (XBF) {
            if (tid < 128) {
                int r = tid >> 1, kc = tid & 1, rr = row0 + r;
                uint4 v = {0, 0, 0, 0};
                if (rr < NN)
                    v = ((const uint4*)Xv)[((long long)rr * K + k0 + 8 * kc) >> 3];
                int kb = 8 * kc;
                As[kb + 0][r] = blo(v.x); As[kb + 1][r] = bhi(v.x);
                As[kb + 2][r] = blo(v.y); As[kb + 3][r] = bhi(v.y);
                As[kb + 4][r] = blo(v.z); As[kb + 5][r] = bhi(v.z);
                As[kb + 6][r] = blo(v.w); As[kb + 7][r] = bhi(v.w);
            }
        } else {
            int r = tid >> 2, kc = tid & 3, rr = row0 + r;
            float4 v = {0.f, 0.f, 0.f, 0.f};
            if (rr < NN)
                v = *(const float4*)((const float*)Xv + (long long)rr * K + k0 + 4 * kc);
            int kb = 4 * kc;
            As[kb + 0][r] = v.x; As[kb + 1][r] = v.y;
            As[kb + 2][r] = v.z; As[kb + 3][r] = v.w;
        }
        // stage B
#pragma unroll
        for (int j = 0; j < (KT * CN / 4) / 256; j++) {
            int q = tid + 256 * j;
            int kk = q / (CN / 4), c4 = q % (CN / 4);
            *(float4*)&Bs[kk][4 * c4] = *(const float4*)&W[(long long)(k0 + kk) * CN + 4 * c4];
        }
        __syncthreads();
#pragma unroll
        for (int kk = 0; kk < KT; kk++) {
            float4 av = *(const float4*)&As[kk][ty * 4];
            float am[4] = {av.x, av.y, av.z, av.w};
            float bm[G][4];
#pragma unroll
            for (int g = 0; g < G; g++) {
                float4 bv = *(const float4*)&Bs[kk][g * 64 + tx * 4];
                bm[g][0] = bv.x; bm[g][1] = bv.y; bm[g][2] = bv.z; bm[g][3] = bv.w;
            }
#pragma unroll
            for (int mi = 0; mi < 4; mi++)
#pragma unroll
                for (int g = 0; g < G; g++)
#pragma unroll
                    for (int ni = 0; ni < 4; ni++)
                        acc[mi][g * 4 + ni] = fmaf(am[mi], bm[g][ni], acc[mi][g * 4 + ni]);
        }
        __syncthreads();
    }
#pragma unroll
    for (int mi = 0; mi < 4; mi++) {
        int r = row0 + ty * 4 + mi;
        if (r < NN) {
            float s = dinv[r];
#pragma unroll
            for (int g = 0; g < G; g++) {
                uint2 u;
                u.x = bpack(s * acc[mi][g * 4 + 0], s * acc[mi][g * 4 + 1]);
                u.y = bpack(s * acc[mi][g * 4 + 2], s * acc[mi][g * 4 + 3]);
                long long elem = (long long)r * CN + g * 64 + tx * 4;
                *(uint2*)(outb + (elem >> 1)) = u;
            }
        }
    }
}

// ---- Layer-1 aggregate: out1 = relu(dinv*(self + sum_in h1) + b). bf16 in/out.
// 16 lanes/node (8 ch each), 16 nodes/block.
__global__ __launch_bounds__(256) void k_gather_relu(const uint4* __restrict__ h,
                                                     const int* __restrict__ csr,
                                                     const int* __restrict__ rowstart,
                                                     const int* __restrict__ cnt,
                                                     const float* __restrict__ dinv,
                                                     const float* __restrict__ bias,
                                                     uint4* __restrict__ out) {
    int tid = threadIdx.x;
    int node = blockIdx.x * 16 + (tid >> 4);
    int cl = tid & 15;
    if (node >= NN) return;
    int beg = rowstart[node], n = cnt[node];
    float acc[8];
    {
        uint4 v = h[(long long)node * 16 + cl];
        acc[0] = blo(v.x); acc[1] = bhi(v.x); acc[2] = blo(v.y); acc[3] = bhi(v.y);
        acc[4] = blo(v.z); acc[5] = bhi(v.z); acc[6] = blo(v.w); acc[7] = bhi(v.w);
    }
    int j = 0;
    for (; j + 3 < n; j += 4) {
        int a0 = csr[beg + j], a1 = csr[beg + j + 1];
        int a2 = csr[beg + j + 2], a3 = csr[beg + j + 3];
        uint4 v0 = h[(long long)a0 * 16 + cl], v1 = h[(long long)a1 * 16 + cl];
        uint4 v2 = h[(long long)a2 * 16 + cl], v3 = h[(long long)a3 * 16 + cl];
        acc[0] += blo(v0.x); acc[1] += bhi(v0.x); acc[2] += blo(v0.y); acc[3] += bhi(v0.y);
        acc[4] += blo(v0.z); acc[5] += bhi(v0.z); acc[6] += blo(v0.w); acc[7] += bhi(v0.w);
        acc[0] += blo(v1.x); acc[1] += bhi(v1.x); acc[2] += blo(v1.y); acc[3] += bhi(v1.y);
        acc[4] += blo(v1.z); acc[5] += bhi(v1.z); acc[6] += blo(v1.w); acc[7] += bhi(v1.w);
        acc[0] += blo(v2.x); acc[1] += bhi(v2.x); acc[2] += blo(v2.y); acc[3] += bhi(v2.y);
        acc[4] += blo(v2.z); acc[5] += bhi(v2.z); acc[6] += blo(v2.w); acc[7] += bhi(v2.w);
        acc[0] += blo(v3.x); acc[1] += bhi(v3.x); acc[2] += blo(v3.y); acc[3] += bhi(v3.y);
        acc[4] += blo(v3.z); acc[5] += bhi(v3.z); acc[6] += blo(v3.w); acc[7] += bhi(v3.w);
    }
    for (; j < n; j++) {
        uint4 v = h[(long long)csr[beg + j] * 16 + cl];
        acc[0] += blo(v.x); acc[1] += bhi(v.x); acc[2] += blo(v.y); acc[3] += bhi(v.y);
        acc[4] += blo(v.z); acc[5] += bhi(v.z); acc[6] += blo(v.w); acc[7] += bhi(v.w);
    }
    float d = dinv[node];
    float4 b0 = *(const float4*)&bias[cl * 8];
    float4 b1 = *(const float4*)&bias[cl * 8 + 4];
    float r0 = fmaxf(fmaf(d, acc[0], b0.x), 0.f), r1 = fmaxf(fmaf(d, acc[1], b0.y), 0.f);
    float r2 = fmaxf(fmaf(d, acc[2], b0.z), 0.f), r3 = fmaxf(fmaf(d, acc[3], b0.w), 0.f);
    float r4 = fmaxf(fmaf(d, acc[4], b1.x), 0.f), r5 = fmaxf(fmaf(d, acc[5], b1.y), 0.f);
    float r6 = fmaxf(fmaf(d, acc[6], b1.z), 0.f), r7 = fmaxf(fmaf(d, acc[7], b1.w), 0.f);
    uint4 o;
    o.x = bpack(r0, r1); o.y = bpack(r2, r3); o.z = bpack(r4, r5); o.w = bpack(r6, r7);
    out[(long long)node * 16 + cl] = o;
}

// ---- Layer-2 aggregate + bias + log_softmax. bf16 in, f32 out.
// 8 lanes/node (8 ch each), 32 nodes/block; shfl_xor reduce within 8-lane group.
__global__ __launch_bounds__(256) void k_gather_lsm(const uint4* __restrict__ h,
                                                    const int* __restrict__ csr,
                                                    const int* __restrict__ rowstart,
                                                    const int* __restrict__ cnt,
                                                    const float* __restrict__ dinv,
                                                    const float* __restrict__ bias,
                                                    float* __restrict__ out) {
    int tid = threadIdx.x;
    int node = blockIdx.x * 32 + (tid >> 3);
    int cl = tid & 7;
    if (node >= NN) return;
    int beg = rowstart[node], n = cnt[node];
    float acc[8];
    {
        uint4 v = h[(long long)node * 8 + cl];
        acc[0] = blo(v.x); acc[1] = bhi(v.x); acc[2] = blo(v.y); acc[3] = bhi(v.y);
        acc[4] = blo(v.z); acc[5] = bhi(v.z); acc[6] = blo(v.w); acc[7] = bhi(v.w);
    }
    int j = 0;
    for (; j + 3 < n; j += 4) {
        int a0 = csr[beg + j], a1 = csr[beg + j + 1];
        int a2 = csr[beg + j + 2], a3 = csr[beg + j + 3];
        uint4 v0 = h[(long long)a0 * 8 + cl], v1 = h[(long long)a1 * 8 + cl];
        uint4 v2 = h[(long long)a2 * 8 + cl], v3 = h[(long long)a3 * 8 + cl];
        acc[0] += blo(v0.x); acc[1] += bhi(v0.x); acc[2] += blo(v0.y); acc[3] += bhi(v0.y);
        acc[4] += blo(v0.z); acc[5] += bhi(v0.z); acc[6] += blo(v0.w); acc[7] += bhi(v0.w);
        acc[0] += blo(v1.x); acc[1] += bhi(v1.x); acc[2] += blo(v1.y); acc[3] += bhi(v1.y);
        acc[4] += blo(v1.z); acc[5] += bhi(v1.z); acc[6] += blo(v1.w); acc[7] += bhi(v1.w);
        acc[0] += blo(v2.x); acc[1] += bhi(v2.x); acc[2] += blo(v2.y); acc[3] += bhi(v2.y);
        acc[4] += blo(v2.z); acc[5] += bhi(v2.z); acc[6] += blo(v2.w); acc[7] += bhi(v2.w);
        acc[0] += blo(v3.x); acc[1] += bhi(v3.x); acc[2] += blo(v3.y); acc[3] += bhi(v3.y);
        acc[4] += blo(v3.z); acc[5] += bhi(v3.z); acc[6] += blo(v3.w); acc[7] += bhi(v3.w);
    }
    for (; j < n; j++) {
        uint4 v = h[(long long)csr[beg + j] * 8 + cl];
        acc[0] += blo(v.x); acc[1] += bhi(v.x); acc[2] += blo(v.y); acc[3] += bhi(v.y);
        acc[4] += blo(v.z); acc[5] += bhi(v.z); acc[6] += blo(v.w); acc[7] += bhi(v.w);
    }
    float d = dinv[node];
    float4 b0 = *(const float4*)&bias[cl * 8];
    float4 b1 = *(const float4*)&bias[cl * 8 + 4];
    float t[8];
    t[0] = fmaf(d, acc[0], b0.x); t[1] = fmaf(d, acc[1], b0.y);
    t[2] = fmaf(d, acc[2], b0.z); t[3] = fmaf(d, acc[3], b0.w);
    t[4] = fmaf(d, acc[4], b1.x); t[5] = fmaf(d, acc[5], b1.y);
    t[6] = fmaf(d, acc[6], b1.z); t[7] = fmaf(d, acc[7], b1.w);
    float m = t[0];
#pragma unroll
    for (int i = 1; i < 8; i++) m = fmaxf(m, t[i]);
#pragma unroll
    for (int o = 1; o < 8; o <<= 1) m = fmaxf(m, __shfl_xor(m, o));
    float ex = 0.f;
#pragma unroll
    for (int i = 0; i < 8; i++) ex += __expf(t[i] - m);
#pragma unroll
    for (int o = 1; o < 8; o <<= 1) ex += __shfl_xor(ex, o);
    float l = logf(ex);
    float4 w0 = {t[0] - m - l, t[1] - m - l, t[2] - m - l, t[3] - m - l};
    float4 w1 = {t[4] - m - l, t[5] - m - l, t[6] - m - l, t[7] - m - l};
    *(float4*)&out[(long long)node * 64 + cl * 8] = w0;
    *(float4*)&out[(long long)node * 64 + cl * 8 + 4] = w1;
}

extern "C" void kernel_launch(void* const* d_in, const int* in_sizes, int n_in,
                              void* d_out, int out_size, void* d_ws, size_t ws_size,
                              hipStream_t stream) {
    const float* x  = (const float*)d_in[0];
    const void*  ei = d_in[1];
    const float* W1 = (const float*)d_in[2];
    const float* b1 = (const float*)d_in[3];
    const float* W2 = (const float*)d_in[4];
    const float* b2 = (const float*)d_in[5];
    float* out = (float*)d_out;

    char* ws = (char*)d_ws;
    float*        dinv     = (float*)(ws + 0x000000);
    int*          flag     = (int*)  (ws + 0x040000);
    int*          cnt      = (int*)  (ws + 0x050000);
    int*          rowstart = (int*)  (ws + 0x090000);
    int*          cur      = (int*)  (ws + 0x0D0000);
    int*          bsum     = (int*)  (ws + 0x110000);
    int*          csr      = (int*)  (ws + 0x120000);   // 6.4 MB
    unsigned int* h1       = (unsigned int*)(ws + 0x740000);   // bf16 12.8 MB (h1, then h2)
    unsigned int* out1     = (unsigned int*)(ws + 0x1400000);  // bf16 12.8 MB

    k_detect<<<1, 64, 0, stream>>>((const unsigned int*)ei, flag);
    hipMemsetAsync(cnt, 0, (size_t)NN * 4, stream);
    k_count<<<(NE + 255) / 256, 256, 0, stream>>>(ei, flag, cnt);
    k_scan1<<<NB, 256, 0, stream>>>(cnt, rowstart, bsum);
    k_scan2<<<1, 256, 0, stream>>>(bsum);
    k_scan3<<<NB, 256, 0, stream>>>(rowstart, bsum, cur);
    k_dinv<<<NB, 256, 0, stream>>>(cnt, dinv);
    k_fill<<<(NE + 255) / 256, 256, 0, stream>>>(ei, flag, cur, csr);

    // Layer 1: h1 = bf16(dinv .* (x@W1)); out1 = bf16(relu(dinv.*(agg+self) + b1))
    k_gemm_scale<256, 128, false><<<(NN + 63) / 64, 256, 0, stream>>>(x, W1, dinv, h1);
    k_gather_relu<<<(NN + 15) / 16, 256, 0, stream>>>((const uint4*)h1, csr, rowstart, cnt,
                                                      dinv, b1, (uint4*)out1);

    // Layer 2: h2 = bf16(dinv .* (out1@W2)); out = log_softmax(dinv.*(agg+self) + b2)
    k_gemm_scale<128, 64, true><<<(NN + 63) / 64, 256, 0, stream>>>(out1, W2, dinv, h1);
    k_gather_lsm<<<(NN + 31) / 32, 256, 0, stream>>>((const uint4*)h1, csr, rowstart, cnt,
                                                     dinv, b2, out);
}